// Round 1
// baseline (51534.351 us; speedup 1.0000x reference)
//
#include <hip/hip_runtime.h>

#define TT 512
#define DD 76
#define HH 256
#define NC 25
#define RB 16        // batch rows per block
#define NBLK 32
#define NTH 1024
#define K1 352       // L1 virtual K: 76 x | 256 h1 | 20 zero-pad
#define K2 512       // L2 K: 256 h1 | 256 h2
#define AS1 360      // LDS u16 stride, L1 act planes
#define AS2 520      // LDS u16 stride, L2 act planes
#define W1ROW (2*K1) // u16 per weight row: [hi K1 | lo K1]
#define W2ROW (2*K2)

typedef unsigned short u16;
typedef unsigned int u32;
typedef __attribute__((ext_vector_type(8))) short bf16x8;
typedef __attribute__((ext_vector_type(4))) float f32x4;

__device__ __forceinline__ float bf2f(u16 v) {
  union { u32 u; float f; } c; c.u = ((u32)v) << 16; return c.f;
}
__device__ __forceinline__ u16 f2bf(float f) {
  union { u32 u; float f; } c; c.f = f;
  u32 r = c.u + 0x7FFFu + ((c.u >> 16) & 1u);   // RNE
  return (u16)(r >> 16);
}
__device__ __forceinline__ void split2(float f, u16& h, u16& l) {
  u16 hh = f2bf(f);
  float r = f - bf2f(hh);
  h = hh; l = f2bf(r);
}
__device__ __forceinline__ float tanh_f(float v) {
  float e = __expf(2.0f * v);
  return 1.0f - 2.0f / (e + 1.0f);
}
// sigmoid(v) = 1/(1+e^-v); tanh(v) = 1 - 2/(e^{2v}+1)  (same numerics as before)
__device__ __forceinline__ float gact(float v, bool is_tanh) {
  float e = __expf(is_tanh ? 2.0f * v : -v);
  float inv = 1.0f / (1.0f + e);
  return is_tanh ? 1.0f - 2.0f * inv : inv;
}
__device__ __forceinline__ float pick4(int m, float a, float b, float c, float d) {
  return m == 0 ? a : (m == 1 ? b : (m == 2 ? c : d));
}

// ---- repack: fp32 [k][4H] -> bf16 hi/lo planes, layout [c][hi K | lo K] ----
// column permutation c = 4*unit + gate  (src col = gate*HH + unit)
__global__ void repack_kernel(const float* __restrict__ Wi1, const float* __restrict__ Wh1,
                              const float* __restrict__ Wi2, const float* __restrict__ Wh2,
                              u16* __restrict__ w1g, u16* __restrict__ w2g) {
  int idx = blockIdx.x * blockDim.x + threadIdx.x;
  const int N1 = 1024 * K1;
  if (idx < N1) {
    int c = idx / K1, k = idx - c * K1;
    int src = (c & 3) * HH + (c >> 2);
    float v = 0.f;
    if (k < DD) v = Wi1[k * 1024 + src];
    else if (k < DD + HH) v = Wh1[(k - DD) * 1024 + src];
    u16 h, l; split2(v, h, l);
    w1g[(size_t)c * W1ROW + k] = h;
    w1g[(size_t)c * W1ROW + K1 + k] = l;
  } else if (idx < N1 + 1024 * K2) {
    int d = idx - N1;
    int c = d >> 9, k = d & 511;
    int src = (c & 3) * HH + (c >> 2);
    float v = (k < HH) ? Wi2[k * 1024 + src] : Wh2[(k - HH) * 1024 + src];
    u16 h, l; split2(v, h, l);
    w2g[(size_t)c * W2ROW + k] = h;
    w2g[(size_t)c * W2ROW + K2 + k] = l;
  }
}

// one K-chunk x one N-tile: 3-term split-fp32 MFMA, B streamed from global (L2-hot)
#define MT(I, WP, KO, KLO)                                                     \
  {                                                                            \
    bf16x8 bh = *(const bf16x8*)((WP) + (KO));                                 \
    bf16x8 bl = *(const bf16x8*)((WP) + (KLO) + (KO));                         \
    aH[I] = __builtin_amdgcn_mfma_f32_16x16x32_bf16(ah, bh, aH[I], 0, 0, 0);   \
    aL[I] = __builtin_amdgcn_mfma_f32_16x16x32_bf16(ah, bl, aL[I], 0, 0, 0);   \
    aL[I] = __builtin_amdgcn_mfma_f32_16x16x32_bf16(al, bh, aL[I], 0, 0, 0);   \
  }

// Gate evaluation, de-redundified: each lane owns (row = qd*4+j, unit = tile*4+u).
// Lane provides z[j^m] so that after shfl_xor(m) it receives row qd*4+j, gate j^m.
#define GATE_TILE(I, CS, STORES)                                               \
  {                                                                            \
    f32x4 zv = aH[I] + aL[I];                                                  \
    float s0 = pick4(j,     zv[0], zv[1], zv[2], zv[3]);                       \
    float s1 = pick4(j ^ 1, zv[0], zv[1], zv[2], zv[3]);                       \
    float s2 = pick4(j ^ 2, zv[0], zv[1], zv[2], zv[3]);                       \
    float s3 = pick4(j ^ 3, zv[0], zv[1], zv[2], zv[3]);                       \
    float v1 = __shfl_xor(s1, 1);                                              \
    float v2 = __shfl_xor(s2, 2);                                              \
    float v3 = __shfl_xor(s3, 3);                                              \
    float t0 = gact(s0, j == 2);                                               \
    float t1 = gact(v1, (j ^ 1) == 2);                                         \
    float t2 = gact(v2, (j ^ 2) == 2);                                         \
    float t3 = gact(v3, (j ^ 3) == 2);                                         \
    float ig = pick4(j,     t0, t1, t2, t3);                                   \
    float fg = pick4(j ^ 1, t0, t1, t2, t3);                                   \
    float gg = pick4(j ^ 2, t0, t1, t2, t3);                                   \
    float og = pick4(j ^ 3, t0, t1, t2, t3);                                   \
    float cn = fg * (CS)[I] + ig * gg;                                         \
    (CS)[I] = cn;                                                              \
    float hv = og * tanh_f(cn);                                                \
    u16 hh_, hl_; split2(hv, hh_, hl_);                                        \
    const int hcol = (wv * 4 + I) * 4 + u;                                     \
    STORES                                                                     \
  }

__global__ __launch_bounds__(NTH) void lstm_kernel(
    const float* __restrict__ x,
    const float* __restrict__ b1, const float* __restrict__ b2,
    const float* __restrict__ Wd, const float* __restrict__ bd,
    const u16* __restrict__ w1g, const u16* __restrict__ w2g,
    float* __restrict__ out)
{
  // double-buffered activation planes (hi/lo bf16 split), block-local recurrence
  __shared__ u16 A1h[2][RB][AS1], A1l[2][RB][AS1];  // [x 0..75 | h1 76..331 | pad] 46,080 B
  __shared__ u16 A2h[2][RB][AS2], A2l[2][RB][AS2];  // [h1 0..255 | h2 256..511] 66,560 B

  const int tid = threadIdx.x;
  const int lane = tid & 63;
  const int wv = tid >> 6;        // 0..15 : wave = 4 N-tiles (64 gate cols)
  const int nl = lane & 15;
  const int qd = lane >> 4;       // 0..3
  const int j = nl & 3;           // gate slot of own column / row slot in gate phase
  const int u = nl >> 2;          // unit slot within tile
  const int gr = qd * 4 + j;      // row this lane owns in the gate phase
  const int row0 = blockIdx.x * RB;

  // zero all act planes (zeros double as h1[-1], h2[-1], and the K1 pad)
  for (int i2 = tid; i2 < 2 * RB * AS1; i2 += NTH) {
    (&A1h[0][0][0])[i2] = 0; (&A1l[0][0][0])[i2] = 0;
  }
  for (int i2 = tid; i2 < 2 * RB * AS2; i2 += NTH) {
    (&A2h[0][0][0])[i2] = 0; (&A2l[0][0][0])[i2] = 0;
  }
  __syncthreads();
  // stage x[0] into buffer 0
  if (tid < 304) {
    int xr = tid / 19, xc = tid - xr * 19;
    float4 v_ = *(const float4*)(x + ((size_t)(row0 + xr) * TT + 0) * DD + xc * 4);
    u16 a0, c0_, a1, c1_, a2, c2_, a3, c3_;
    split2(v_.x, a0, c0_); split2(v_.y, a1, c1_);
    split2(v_.z, a2, c2_); split2(v_.w, a3, c3_);
    *(ushort4*)&A1h[0][xr][xc * 4] = make_ushort4(a0, a1, a2, a3);
    *(ushort4*)&A1l[0][xr][xc * 4] = make_ushort4(c0_, c1_, c2_, c3_);
  }

  const int c0 = wv * 64 + nl;    // weight row (= gate col) of tile 0
  float bv1[4], bv2[4];
#pragma unroll
  for (int i = 0; i < 4; ++i) {
    int jg = (c0 + i * 16) >> 2;
    bv1[i] = b1[j * HH + jg];
    bv2[i] = b2[j * HH + jg];
  }
  const u16* w1p0 = w1g + (size_t)(c0 +  0) * W1ROW + qd * 8;
  const u16* w1p1 = w1g + (size_t)(c0 + 16) * W1ROW + qd * 8;
  const u16* w1p2 = w1g + (size_t)(c0 + 32) * W1ROW + qd * 8;
  const u16* w1p3 = w1g + (size_t)(c0 + 48) * W1ROW + qd * 8;
  const u16* w2p0 = w2g + (size_t)(c0 +  0) * W2ROW + qd * 8;
  const u16* w2p1 = w2g + (size_t)(c0 + 16) * W2ROW + qd * 8;
  const u16* w2p2 = w2g + (size_t)(c0 + 32) * W2ROW + qd * 8;
  const u16* w2p3 = w2g + (size_t)(c0 + 48) * W2ROW + qd * 8;

  float cs1[4] = {0.f, 0.f, 0.f, 0.f}, cs2[4] = {0.f, 0.f, 0.f, 0.f};
  __syncthreads();

#pragma unroll 1
  for (int t = 0; t < TT; ++t) {
    const int rb = t & 1, wb = rb ^ 1;

    // ---------- L1[t]: z1 = A1[rb] @ W1 ----------
    {
      f32x4 aH[4] = { {bv1[0],bv1[0],bv1[0],bv1[0]}, {bv1[1],bv1[1],bv1[1],bv1[1]},
                      {bv1[2],bv1[2],bv1[2],bv1[2]}, {bv1[3],bv1[3],bv1[3],bv1[3]} };
      f32x4 aL[4] = { {0,0,0,0}, {0,0,0,0}, {0,0,0,0}, {0,0,0,0} };
      const u16* a1h = &A1h[rb][nl][0] + qd * 8;
      const u16* a1l = &A1l[rb][nl][0] + qd * 8;
#pragma unroll 4
      for (int ks = 0; ks < 11; ++ks) {
        const int ko = ks * 32;
        bf16x8 ah = *(const bf16x8*)(a1h + ko);
        bf16x8 al = *(const bf16x8*)(a1l + ko);
        MT(0, w1p0, ko, K1)
        MT(1, w1p1, ko, K1)
        MT(2, w1p2, ko, K1)
        MT(3, w1p3, ko, K1)
      }
      // h1[t] -> A1[wb] (for L1[t+1]) and A2[rb] (for L2[t])
      GATE_TILE(0, cs1, { A1h[wb][gr][76+hcol]=hh_; A1l[wb][gr][76+hcol]=hl_;
                          A2h[rb][gr][hcol]=hh_;    A2l[rb][gr][hcol]=hl_; })
      GATE_TILE(1, cs1, { A1h[wb][gr][76+hcol]=hh_; A1l[wb][gr][76+hcol]=hl_;
                          A2h[rb][gr][hcol]=hh_;    A2l[rb][gr][hcol]=hl_; })
      GATE_TILE(2, cs1, { A1h[wb][gr][76+hcol]=hh_; A1l[wb][gr][76+hcol]=hl_;
                          A2h[rb][gr][hcol]=hh_;    A2l[rb][gr][hcol]=hl_; })
      GATE_TILE(3, cs1, { A1h[wb][gr][76+hcol]=hh_; A1l[wb][gr][76+hcol]=hl_;
                          A2h[rb][gr][hcol]=hh_;    A2l[rb][gr][hcol]=hl_; })
    }
    __syncthreads();   // publish h1[t]

    // ---------- L2[t]: z2 = A2[rb] @ W2 ; prefetch x[t+1] ----------
    {
      float4 xv;
      const bool hx = (t + 1 < TT) && (tid < 304);
      const int xr = tid / 19, xc = tid - xr * 19;
      if (hx) xv = *(const float4*)(x + ((size_t)(row0 + xr) * TT + (t + 1)) * DD + xc * 4);

      f32x4 aH[4] = { {bv2[0],bv2[0],bv2[0],bv2[0]}, {bv2[1],bv2[1],bv2[1],bv2[1]},
                      {bv2[2],bv2[2],bv2[2],bv2[2]}, {bv2[3],bv2[3],bv2[3],bv2[3]} };
      f32x4 aL[4] = { {0,0,0,0}, {0,0,0,0}, {0,0,0,0}, {0,0,0,0} };
      const u16* a2h = &A2h[rb][nl][0] + qd * 8;
      const u16* a2l = &A2l[rb][nl][0] + qd * 8;
#pragma unroll 4
      for (int ks = 0; ks < 16; ++ks) {
        const int ko = ks * 32;
        bf16x8 ah = *(const bf16x8*)(a2h + ko);
        bf16x8 al = *(const bf16x8*)(a2l + ko);
        MT(0, w2p0, ko, K2)
        MT(1, w2p1, ko, K2)
        MT(2, w2p2, ko, K2)
        MT(3, w2p3, ko, K2)
      }
      // h2[t] -> A2[wb] cols 256.. (for L2[t+1]; t=511 lands in buf 0 for the head)
      GATE_TILE(0, cs2, { A2h[wb][gr][256+hcol]=hh_; A2l[wb][gr][256+hcol]=hl_; })
      GATE_TILE(1, cs2, { A2h[wb][gr][256+hcol]=hh_; A2l[wb][gr][256+hcol]=hl_; })
      GATE_TILE(2, cs2, { A2h[wb][gr][256+hcol]=hh_; A2l[wb][gr][256+hcol]=hl_; })
      GATE_TILE(3, cs2, { A2h[wb][gr][256+hcol]=hh_; A2l[wb][gr][256+hcol]=hl_; })

      if (hx) {   // write x[t+1] into A1[wb] cols 0..75 (read next L1, after barrier)
        u16 a0, d0, a1, d1, a2, d2, a3, d3;
        split2(xv.x, a0, d0); split2(xv.y, a1, d1);
        split2(xv.z, a2, d2); split2(xv.w, a3, d3);
        *(ushort4*)&A1h[wb][xr][xc * 4] = make_ushort4(a0, a1, a2, a3);
        *(ushort4*)&A1l[wb][xr][xc * 4] = make_ushort4(d0, d1, d2, d3);
      }
    }
    __syncthreads();   // publish h2[t] + x[t+1]
  }

  // ---------- dense head: logits = h2[511] @ Wd + bd (h2[511] in A2[0] cols 256..) ----------
  if (tid < RB * NC) {
    const int r = tid / NC, n = tid - r * NC;
    float s = bd[n];
#pragma unroll 8
    for (int k = 0; k < HH; ++k)
      s += (bf2f(A2h[0][r][256 + k]) + bf2f(A2l[0][r][256 + k])) * Wd[k * NC + n];
    out[(size_t)(row0 + r) * NC + n] = s;
  }
}

extern "C" void kernel_launch(void* const* d_in, const int* in_sizes, int n_in,
                              void* d_out, int out_size, void* d_ws, size_t ws_size,
                              hipStream_t stream) {
  const float* x   = (const float*)d_in[0];
  const float* Wi1 = (const float*)d_in[1];
  const float* Wh1 = (const float*)d_in[2];
  const float* b1  = (const float*)d_in[3];
  const float* Wi2 = (const float*)d_in[4];
  const float* Wh2 = (const float*)d_in[5];
  const float* b2  = (const float*)d_in[6];
  const float* Wd  = (const float*)d_in[7];
  const float* bd  = (const float*)d_in[8];

  char* ws = (char*)d_ws;
  // ws layout: w1g [1024][704] u16 = 1,441,792 B ; w2g [1024][1024] u16 = 2,097,152 B
  u16* w1g = (u16*)ws;
  u16* w2g = (u16*)(ws + 1441792u);
  float* out = (float*)d_out;

  const int total = 1024 * K1 + 1024 * K2;
  repack_kernel<<<(total + 255) / 256, 256, 0, stream>>>(Wi1, Wh1, Wi2, Wh2, w1g, w2g);
  lstm_kernel<<<NBLK, NTH, 0, stream>>>(x, b1, b2, Wd, bd, w1g, w2g, out);
}

// Round 2
// 7066.053 us; speedup vs baseline: 7.2932x; 7.2932x over previous
//
#include <hip/hip_runtime.h>

#define BB 512
#define TT 512
#define DD 76
#define HH 256
#define NC 25
#define NBLK 256
#define NTHREADS 512
#define BBHH (BB * HH)   // u32 words per h slot

#define K1 352      // L1 virtual K: 76 x | 256 h | 20 zero-pad
#define K2 512      // L2 K: 256 h1 | 256 h2
#define WS1 360     // LDS k-stride (u16) for W1 planes
#define WS2 520     // LDS k-stride (u16) for W2 planes
#define ACT_S 136   // LDS act row stride (u16)

typedef unsigned short u16;
typedef unsigned int u32;
typedef unsigned long long u64;
typedef __attribute__((ext_vector_type(8))) short bf16x8;
typedef __attribute__((ext_vector_type(4))) float f32x4;

__device__ __forceinline__ float bf2f(u16 v) {
  union { u32 u; float f; } c; c.u = ((u32)v) << 16; return c.f;
}
__device__ __forceinline__ u16 f2bf(float f) {
  union { u32 u; float f; } c; c.f = f;
  u32 r = c.u + 0x7FFFu + ((c.u >> 16) & 1u);   // RNE
  return (u16)(r >> 16);
}
__device__ __forceinline__ void split2(float f, u16& h, u16& l) {
  u16 hh = f2bf(f);
  float r = f - bf2f(hh);
  h = hh; l = f2bf(r);
}
__device__ __forceinline__ float sigm(float v) { return 1.0f / (1.0f + __expf(-v)); }
__device__ __forceinline__ float tanh_f(float v) {
  float e = __expf(2.0f * v);
  return 1.0f - 2.0f / (e + 1.0f);
}
__device__ __forceinline__ float pick4(int m, float a, float b, float c, float d) {
  return m == 0 ? a : (m == 1 ? b : (m == 2 ? c : d));
}

// ---- coherence-point (IF$) transport for h: relaxed agent atomics, NO fences ----
// Stores are sc0/sc1 write-through; they retire (vmcnt) at the coherence point, and
// every consumer load also goes to the coherence point -> no L2 flush/inv needed.
__device__ __forceinline__ u64 ald2(const u32* p) {
  return __hip_atomic_load((const u64*)p, __ATOMIC_RELAXED, __HIP_MEMORY_SCOPE_AGENT);
}
__device__ __forceinline__ u32 ald1(const u32* p) {
  return __hip_atomic_load(p, __ATOMIC_RELAXED, __HIP_MEMORY_SCOPE_AGENT);
}
__device__ __forceinline__ void ast1(u32* p, u32 v) {
  __hip_atomic_store(p, v, __ATOMIC_RELAXED, __HIP_MEMORY_SCOPE_AGENT);
}

// ---- distributed flag sync: 32 flags/group, each on own 128B line ----
__device__ __forceinline__ void wait_flags(const u32* fbase, u32 target) {
  const int tid = threadIdx.x;
  if (tid < 32) {
    const u32* p = fbase + tid * 32;
    while (__hip_atomic_load(p, __ATOMIC_RELAXED, __HIP_MEMORY_SCOPE_AGENT) < target)
      __builtin_amdgcn_s_sleep(1);
  }
  __syncthreads();   // execution-orders all waves' subsequent h loads after the poll
}
__device__ __forceinline__ void post_flag(u32* slot, u32 val) {
  __syncthreads();   // all waves' sc1 h-stores vmcnt-drained (reached coherence point)
  if (threadIdx.x == 0)
    __hip_atomic_store(slot, val, __ATOMIC_RELAXED, __HIP_MEMORY_SCOPE_AGENT);
}

// ---- repack: fp32 [k][4H] -> hi/lo bf16 planes, layout [c=4j+g][k], L1 zero-pad ----
__global__ void repack_kernel(const float* __restrict__ Wi1, const float* __restrict__ Wh1,
                              const float* __restrict__ Wi2, const float* __restrict__ Wh2,
                              u16* __restrict__ w1hg, u16* __restrict__ w1lg,
                              u16* __restrict__ w2hg, u16* __restrict__ w2lg) {
  int idx = blockIdx.x * blockDim.x + threadIdx.x;
  const int N1 = 1024 * K1;
  if (idx < N1) {
    int c = idx / K1, k = idx - c * K1;
    int src = (c & 3) * HH + (c >> 2);
    float v = 0.f;
    if (k < DD) v = Wi1[k * 1024 + src];
    else if (k < DD + HH) v = Wh1[(k - DD) * 1024 + src];
    u16 h, l; split2(v, h, l);
    w1hg[idx] = h; w1lg[idx] = l;
  } else if (idx < N1 + 1024 * K2) {
    int d = idx - N1;
    int c = d >> 9, k = d & 511;
    int src = (c & 3) * HH + (c >> 2);
    float v = (k < HH) ? Wi2[k * 1024 + src] : Wh2[(k - HH) * 1024 + src];
    u16 h, l; split2(v, h, l);
    w2hg[d] = h; w2lg[d] = l;
  }
}

// prefetch a full 128-wide h chunk (u32 words = hi|lo<<16) into regs
#define PF_H(HW, KOFS)                                                             \
  _Pragma("unroll")                                                                \
  for (int k_ = 0; k_ < 4; ++k_) {                                                 \
    int i_ = tid + k_ * NTHREADS;                                                  \
    int r_ = i_ >> 5, c_ = i_ & 31;                                                \
    const u32* p_ = (HW) + (size_t)(row0 + r_) * HH + (KOFS) + c_ * 4;             \
    pfa[k_][0] = ald2(p_); pfa[k_][1] = ald2(p_ + 2);                              \
  }
#define WR_H()                                                                     \
  _Pragma("unroll")                                                                \
  for (int k_ = 0; k_ < 4; ++k_) {                                                 \
    int i_ = tid + k_ * NTHREADS;                                                  \
    int r_ = i_ >> 5, c_ = i_ & 31;                                                \
    u32 w0_ = (u32)pfa[k_][0], w1_ = (u32)(pfa[k_][0] >> 32);                      \
    u32 w2_ = (u32)pfa[k_][1], w3_ = (u32)(pfa[k_][1] >> 32);                      \
    *(ushort4*)&ath[r_ * ACT_S + c_ * 4] =                                         \
        make_ushort4((u16)w0_, (u16)w1_, (u16)w2_, (u16)w3_);                      \
    *(ushort4*)&atl[r_ * ACT_S + c_ * 4] =                                         \
        make_ushort4((u16)(w0_ >> 16), (u16)(w1_ >> 16),                           \
                     (u16)(w2_ >> 16), (u16)(w3_ >> 16));                          \
  }

// L1 chunk0: x[t] fp32 (split here) in cols 0..75, h1[0..51] in 76..127
#define STAGE_C0(TTT, H1W)                                                         \
  for (int i_ = tid; i_ < 64 * 19; i_ += NTHREADS) {                               \
    int r_ = i_ / 19, c_ = i_ - r_ * 19;                                           \
    float4 v_ = *(const float4*)(x + ((size_t)(row0 + r_) * TT + (TTT)) * DD + c_ * 4); \
    u16 h0_, l0_, h1_, l1_, h2_, l2_, h3_, l3_;                                    \
    split2(v_.x, h0_, l0_); split2(v_.y, h1_, l1_);                                \
    split2(v_.z, h2_, l2_); split2(v_.w, h3_, l3_);                                \
    *(ushort4*)&ath[r_ * ACT_S + c_ * 4] = make_ushort4(h0_, h1_, h2_, h3_);       \
    *(ushort4*)&atl[r_ * ACT_S + c_ * 4] = make_ushort4(l0_, l1_, l2_, l3_);       \
  }                                                                                \
  for (int i_ = tid; i_ < 64 * 13; i_ += NTHREADS) {                               \
    int r_ = i_ / 13, c_ = i_ - r_ * 13;                                           \
    u32 w0_ = 0, w1_ = 0, w2_ = 0, w3_ = 0;                                        \
    if ((H1W) != nullptr) {                                                        \
      const u32* p_ = (H1W) + (size_t)(row0 + r_) * HH + c_ * 4;                   \
      u64 q0_ = ald2(p_), q1_ = ald2(p_ + 2);                                      \
      w0_ = (u32)q0_; w1_ = (u32)(q0_ >> 32);                                      \
      w2_ = (u32)q1_; w3_ = (u32)(q1_ >> 32);                                      \
    }                                                                              \
    *(ushort4*)&ath[r_ * ACT_S + 76 + c_ * 4] =                                    \
        make_ushort4((u16)w0_, (u16)w1_, (u16)w2_, (u16)w3_);                      \
    *(ushort4*)&atl[r_ * ACT_S + 76 + c_ * 4] =                                    \
        make_ushort4((u16)(w0_ >> 16), (u16)(w1_ >> 16),                           \
                     (u16)(w2_ >> 16), (u16)(w3_ >> 16));                          \
  }

// L1 chunk2: h1[180..255] in cols 0..75, zeros in 76..127 (zero-weight pad rows)
#define STAGE_C2(H1W)                                                              \
  for (int i_ = tid; i_ < 64 * 32; i_ += NTHREADS) {                               \
    int r_ = i_ >> 5, c_ = i_ & 31;                                                \
    u32 w0_ = 0, w1_ = 0, w2_ = 0, w3_ = 0;                                        \
    if (c_ < 19) {                                                                 \
      const u32* p_ = (H1W) + (size_t)(row0 + r_) * HH + 180 + c_ * 4;             \
      u64 q0_ = ald2(p_), q1_ = ald2(p_ + 2);                                      \
      w0_ = (u32)q0_; w1_ = (u32)(q0_ >> 32);                                      \
      w2_ = (u32)q1_; w3_ = (u32)(q1_ >> 32);                                      \
    }                                                                              \
    *(ushort4*)&ath[r_ * ACT_S + c_ * 4] =                                         \
        make_ushort4((u16)w0_, (u16)w1_, (u16)w2_, (u16)w3_);                      \
    *(ushort4*)&atl[r_ * ACT_S + c_ * 4] =                                         \
        make_ushort4((u16)(w0_ >> 16), (u16)(w1_ >> 16),                           \
                     (u16)(w2_ >> 16), (u16)(w3_ >> 16));                          \
  }

// 3-term split-fp32 MFMA over one staged 128-wide chunk
#define MFMA_CHUNK(Bh, Bl, wofs, nks)                                              \
  for (int s_ = 0; s_ < (nks); ++s_) {                                             \
    const int ko_ = s_ * 32 + qd * 8;                                              \
    bf16x8 a_h = *(const bf16x8*)(wA + ko_);                                       \
    bf16x8 a_l = *(const bf16x8*)(wAl + ko_);                                      \
    bf16x8 b_h = *(const bf16x8*)((Bh) + (wofs) + ko_);                            \
    bf16x8 b_l = *(const bf16x8*)((Bl) + (wofs) + ko_);                            \
    accA = __builtin_amdgcn_mfma_f32_16x16x32_bf16(a_h, b_h, accA, 0, 0, 0);       \
    accB = __builtin_amdgcn_mfma_f32_16x16x32_bf16(a_h, b_l, accB, 0, 0, 0);       \
    accC = __builtin_amdgcn_mfma_f32_16x16x32_bf16(a_l, b_h, accC, 0, 0, 0);       \
  }

#define GATES2(Z, CS, DW)                                                          \
  _Pragma("unroll")                                                                \
  for (int r = 0; r < 4; ++r) {                                                    \
    float zr = (Z)[r];                                                             \
    float s1 = __shfl_xor(zr, 1), s2 = __shfl_xor(zr, 2), s3 = __shfl_xor(zr, 3);  \
    float g0 = pick4(gi, zr, s1, s2, s3);                                          \
    float g1 = pick4(gi ^ 1, zr, s1, s2, s3);                                      \
    float g2 = pick4(gi ^ 2, zr, s1, s2, s3);                                      \
    float g3 = pick4(gi ^ 3, zr, s1, s2, s3);                                      \
    float ig = sigm(g0), fg = sigm(g1), gg = tanh_f(g2), og = sigm(g3);            \
    (CS)[r] = fg * (CS)[r] + ig * gg;                                              \
    float hv = og * tanh_f((CS)[r]);                                               \
    if (gi == 0) {                                                                 \
      u16 hh_, hl_; split2(hv, hh_, hl_);                                          \
      ast1((DW) + (size_t)(rbase + r) * HH + jg, (u32)hh_ | ((u32)hl_ << 16));     \
    }                                                                              \
  }

__global__ __launch_bounds__(NTHREADS) void lstm_kernel(
    const float* __restrict__ x,
    const float* __restrict__ b1, const float* __restrict__ b2,
    const float* __restrict__ Wd, const float* __restrict__ bd,
    const u16* __restrict__ w1hg, const u16* __restrict__ w1lg,
    const u16* __restrict__ w2hg, const u16* __restrict__ w2lg,
    u32* __restrict__ h1w, u32* __restrict__ h2w,
    u32* __restrict__ flags,
    float* __restrict__ out)
{
  __shared__ u16 w1h[32 * WS1], w1l[32 * WS1];     // 46,080 B
  __shared__ u16 w2h[32 * WS2], w2l[32 * WS2];     // 66,560 B
  __shared__ u16 ath[64 * ACT_S], atl[64 * ACT_S]; // 34,816 B (total 147,456)

  const int tid = threadIdx.x;
  const int lane = tid & 63;
  const int wv = tid >> 6;            // 0..7
  const int mf = wv & 3;              // M-frag: rows mf*16..
  const int nf = wv >> 2;             // 0..1: cols nf*16..
  const int nl = lane & 15;
  const int qd = lane >> 4;           // 0..3
  const int bt = blockIdx.x & 7;      // row-group (likely XCD-aligned via %8 dispatch)
  const int jt = blockIdx.x >> 3;     // 0..31 col-group within the group
  const int row0 = bt * 64;

  u32* gAp = flags + bt * 1024;                 // poll bases (32 flags x 32-u32 spacing)
  u32* gBp = flags + 8192 + bt * 1024;
  u32* gAslot = gAp + jt * 32;                  // this block's flags
  u32* gBslot = gBp + jt * 32;

  // ---- stage weight slices to LDS once ----
  for (int i = tid; i < 32 * (K1 / 2); i += NTHREADS) {
    int c = i / 176, kk = i - c * 176;
    ((u32*)&w1h[c * WS1])[kk] = ((const u32*)(w1hg + (size_t)(jt * 32 + c) * K1))[kk];
    ((u32*)&w1l[c * WS1])[kk] = ((const u32*)(w1lg + (size_t)(jt * 32 + c) * K1))[kk];
  }
  for (int i = tid; i < 32 * (K2 / 2); i += NTHREADS) {
    int c = i >> 8, kk = i & 255;
    ((u32*)&w2h[c * WS2])[kk] = ((const u32*)(w2hg + (size_t)(jt * 32 + c) * K2))[kk];
    ((u32*)&w2l[c * WS2])[kk] = ((const u32*)(w2lg + (size_t)(jt * 32 + c) * K2))[kk];
  }

  const int cg_col = jt * 32 + nf * 16 + nl;
  const int jg = cg_col >> 2;
  const int gi = cg_col & 3;
  const float bias1 = b1[gi * HH + jg];
  const float bias2 = b2[gi * HH + jg];
  const int rbase = row0 + mf * 16 + qd * 4;
  float c1s[4] = {0.f, 0.f, 0.f, 0.f}, c2s[4] = {0.f, 0.f, 0.f, 0.f};

  const u16* wA  = ath + (mf * 16 + nl) * ACT_S;
  const u16* wAl = atl + (mf * 16 + nl) * ACT_S;
  const int cl = nf * 16 + nl;
  const u16* wB1h = w1h + cl * WS1;
  const u16* wB1l = w1l + cl * WS1;
  const u16* wB2h = w2h + cl * WS2;
  const u16* wB2l = w2l + cl * WS2;

  // ---- prologue: h1[0] = L1(x[0], 0) -> slot 0; post A=1, B=1 ----
  {
    f32x4 accA = {bias1, bias1, bias1, bias1};
    f32x4 accB = {0.f, 0.f, 0.f, 0.f}, accC = {0.f, 0.f, 0.f, 0.f};
    STAGE_C0(0, (const u32*)nullptr);
    __syncthreads();   // orders weight + act LDS writes before reads
    MFMA_CHUNK(wB1h, wB1l, 0, 4);
    f32x4 z = accA + accB + accC;
    GATES2(z, c1s, h1w);
    __syncthreads();   // h stores drained before flag post
    if (tid == 0) { ast1(gAslot, 1u); ast1(gBslot, 1u); }
  }

  // ---- main loop: phase t = L2[t] then L1[t+1] ----
#pragma unroll 1
  for (int t = 0; t < TT; ++t) {
    const u32* h1cw = h1w + (t & 1) * BBHH;        // h1[t]
    u32* h1nw = h1w + ((t + 1) & 1) * BBHH;        // h1[t+1]
    const u32* h2pw = h2w + ((t + 1) & 1) * BBHH;  // h2[t-1]
    u32* h2cw = h2w + (t & 1) * BBHH;              // h2[t]

    u64 pfa[4][2];

    // ----- L2[t] -----
    {
      f32x4 accA = {bias2, bias2, bias2, bias2};
      f32x4 accB = {0.f, 0.f, 0.f, 0.f}, accC = {0.f, 0.f, 0.f, 0.f};
      wait_flags(gAp, t + 1);                       // h2[t-1] ready; h2-slot write-safe
      if (t > 0) {
        PF_H(h2pw, 0);
        WR_H();
        PF_H(h2pw, 128);
        __syncthreads();
        MFMA_CHUNK(wB2h, wB2l, 256, 4);             // h2 terms
        __syncthreads();
        WR_H();
        wait_flags(gBp, t + 1);                     // h1[t] ready (sync publishes WR)
        PF_H(h1cw, 0);
        MFMA_CHUNK(wB2h, wB2l, 384, 4);
        __syncthreads();
        WR_H();
        PF_H(h1cw, 128);
        __syncthreads();
        MFMA_CHUNK(wB2h, wB2l, 0, 4);               // h1 terms
        __syncthreads();
        WR_H();
        __syncthreads();
        MFMA_CHUNK(wB2h, wB2l, 128, 4);
      } else {
        wait_flags(gBp, 1);
        PF_H(h1cw, 0);
        WR_H();
        PF_H(h1cw, 128);
        __syncthreads();
        MFMA_CHUNK(wB2h, wB2l, 0, 4);
        __syncthreads();
        WR_H();
        __syncthreads();
        MFMA_CHUNK(wB2h, wB2l, 128, 4);
      }
      f32x4 z = accA + accB + accC;
      GATES2(z, c2s, h2cw);
      post_flag(gAslot, t + 2);                     // internal sync also fences act reuse
    }

    // ----- L1[t+1] -----
    if (t < TT - 1) {
      f32x4 accA = {bias1, bias1, bias1, bias1};
      f32x4 accB = {0.f, 0.f, 0.f, 0.f}, accC = {0.f, 0.f, 0.f, 0.f};
      STAGE_C0(t + 1, h1cw);
      PF_H(h1cw, 52);                               // chunk1 = h1[52..179]
      __syncthreads();
      MFMA_CHUNK(wB1h, wB1l, 0, 4);
      __syncthreads();
      WR_H();
      __syncthreads();
      MFMA_CHUNK(wB1h, wB1l, 128, 4);
      __syncthreads();
      STAGE_C2(h1cw);                               // h1[180..255] + zero pad
      __syncthreads();
      MFMA_CHUNK(wB1h, wB1l, 256, 3);
      f32x4 z = accA + accB + accC;
      GATES2(z, c1s, h1nw);
      post_flag(gBslot, t + 2);
    }
  }

  // ---- dense head: logits = h2[511] @ Wd + bd (slot 1) ----
  wait_flags(gAp, TT + 1);
  if (tid < 2 * NC) {
    int r = row0 + jt * 2 + tid / NC;
    int n = tid - (tid / NC) * NC;
    float s = bd[n];
    const u32* fw = h2w + BBHH + (size_t)r * HH;
#pragma unroll 8
    for (int k = 0; k < HH; ++k) {
      u32 w = ald1(fw + k);
      s += (bf2f((u16)w) + bf2f((u16)(w >> 16))) * Wd[k * NC + n];
    }
    out[r * NC + n] = s;
  }
}

extern "C" void kernel_launch(void* const* d_in, const int* in_sizes, int n_in,
                              void* d_out, int out_size, void* d_ws, size_t ws_size,
                              hipStream_t stream) {
  const float* x   = (const float*)d_in[0];
  const float* Wi1 = (const float*)d_in[1];
  const float* Wh1 = (const float*)d_in[2];
  const float* b1  = (const float*)d_in[3];
  const float* Wi2 = (const float*)d_in[4];
  const float* Wh2 = (const float*)d_in[5];
  const float* b2  = (const float*)d_in[6];
  const float* Wd  = (const float*)d_in[7];
  const float* bd  = (const float*)d_in[8];

  char* ws = (char*)d_ws;
  // ws layout (bytes):
  //   [0, 1M)          h1w ping-pong u32 words (hi|lo<<16) [2][512][256]
  //   [1M, 2M)         h2w
  //   [2M, ..)         w1hg/w1lg (720,896 each), w2hg/w2lg (1,048,576 each)
  //   [5,636,096, +64K) flag arrays A and B (zeroed every call)
  u32* h1w = (u32*)(ws);
  u32* h2w = (u32*)(ws + 1048576u);
  u16* w1hg = (u16*)(ws + 2097152u);
  u16* w1lg = (u16*)(ws + 2097152u + 720896u);
  u16* w2hg = (u16*)(ws + 2097152u + 2u * 720896u);
  u16* w2lg = (u16*)(ws + 2097152u + 2u * 720896u + 1048576u);
  u32* flags = (u32*)(ws + 5636096u);
  float* out = (float*)d_out;

  hipMemsetAsync((void*)flags, 0, 65536, stream);
  const int total = 1024 * K1 + 1024 * K2;
  repack_kernel<<<(total + 255) / 256, 256, 0, stream>>>(
      Wi1, Wh1, Wi2, Wh2, w1hg, w1lg, w2hg, w2lg);

  void* args[] = {
    (void*)&x, (void*)&b1, (void*)&b2, (void*)&Wd, (void*)&bd,
    (void*)&w1hg, (void*)&w1lg, (void*)&w2hg, (void*)&w2lg,
    (void*)&h1w, (void*)&h2w,
    (void*)&flags, (void*)&out
  };
  // Cooperative launch purely for the co-residency guarantee; sync is custom.
  (void)hipLaunchCooperativeKernel((void*)lstm_kernel, dim3(NBLK),
                                   dim3(NTHREADS), args, 0, stream);
}

// Round 3
// 5749.224 us; speedup vs baseline: 8.9637x; 1.2290x over previous
//
#include <hip/hip_runtime.h>

#define BB 512
#define TT 512
#define DD 76
#define HH 256
#define NC 25
#define NBLK 256
#define NTHREADS 512
#define BBHH (BB * HH)   // u32 words per h slot

#define K1 352      // L1 virtual K: 256 h1 | 76 x | 20 zero-pad  (h1 FIRST for reg-reuse)
#define K2 512      // L2 K: 256 h1 | 256 h2
#define WS1 360     // LDS k-stride (u16) for W1 planes
#define WS2 520     // LDS k-stride (u16) for W2 planes

typedef unsigned short u16;
typedef unsigned int u32;
typedef unsigned long long u64;
typedef __attribute__((ext_vector_type(8))) short bf16x8;
typedef __attribute__((ext_vector_type(4))) float f32x4;

__device__ __forceinline__ float bf2f(u16 v) {
  union { u32 u; float f; } c; c.u = ((u32)v) << 16; return c.f;
}
__device__ __forceinline__ u16 f2bf(float f) {
  union { u32 u; float f; } c; c.f = f;
  u32 r = c.u + 0x7FFFu + ((c.u >> 16) & 1u);   // RNE
  return (u16)(r >> 16);
}
__device__ __forceinline__ void split2(float f, u16& h, u16& l) {
  u16 hh = f2bf(f);
  float r = f - bf2f(hh);
  h = hh; l = f2bf(r);
}
__device__ __forceinline__ float tanh_f(float v) {
  float e = __expf(2.0f * v);
  return 1.0f - 2.0f / (e + 1.0f);
}
__device__ __forceinline__ float gact(float v, bool is_tanh) {
  float e = __expf(is_tanh ? 2.0f * v : -v);
  float inv = 1.0f / (1.0f + e);
  return is_tanh ? 1.0f - 2.0f * inv : inv;
}

// ---- coherence-point (IF$) transport: relaxed agent atomics, NO fences ----
__device__ __forceinline__ u64 ald2(const u32* p) {
  return __hip_atomic_load((const u64*)p, __ATOMIC_RELAXED, __HIP_MEMORY_SCOPE_AGENT);
}
__device__ __forceinline__ u32 ald1(const u32* p) {
  return __hip_atomic_load(p, __ATOMIC_RELAXED, __HIP_MEMORY_SCOPE_AGENT);
}
__device__ __forceinline__ void ast1(u32* p, u32 v) {
  __hip_atomic_store(p, v, __ATOMIC_RELAXED, __HIP_MEMORY_SCOPE_AGENT);
}

// ---- distributed flag sync: 32 flags/group, each on own 128B line ----
__device__ __forceinline__ void wait_flags(const u32* fbase, u32 target) {
  const int tid = threadIdx.x;
  if (tid < 32) {
    const u32* p = fbase + tid * 32;
    while (__hip_atomic_load(p, __ATOMIC_RELAXED, __HIP_MEMORY_SCOPE_AGENT) < target)
      __builtin_amdgcn_s_sleep(1);
  }
  __syncthreads();   // execution-orders subsequent h loads after the poll
}
__device__ __forceinline__ void post_flag(u32* slot, u32 val) {
  __syncthreads();   // all waves' sc-bypass h-stores vmcnt-drained (at coherence point)
  if (threadIdx.x == 0) ast1(slot, val);
}

// packed h word: low16 = bf16-hi part, high16 = bf16-lo part
// build a bf16x8 fragment from 4 u64 (8 packed words) via v_perm
__device__ __forceinline__ bf16x8 hi8(const u64 w[4]) {
  union { u32 u[4]; bf16x8 v; } c;
#pragma unroll
  for (int i = 0; i < 4; ++i)
    c.u[i] = __builtin_amdgcn_perm((u32)(w[i] >> 32), (u32)w[i], 0x05040100u);
  return c.v;
}
__device__ __forceinline__ bf16x8 lo8(const u64 w[4]) {
  union { u32 u[4]; bf16x8 v; } c;
#pragma unroll
  for (int i = 0; i < 4; ++i)
    c.u[i] = __builtin_amdgcn_perm((u32)(w[i] >> 32), (u32)w[i], 0x07060302u);
  return c.v;
}

__device__ __forceinline__ void splitv8(const float* f, bf16x8& vh, bf16x8& vl) {
  union { u16 s[8]; bf16x8 v; } ch, cl;
#pragma unroll
  for (int i = 0; i < 8; ++i) { u16 h_, l_; split2(f[i], h_, l_); ch.s[i] = h_; cl.s[i] = l_; }
  vh = ch.v; vl = cl.v;
}

// ---- repack: fp32 [k][4H] -> hi/lo bf16 planes, layout [c=4j+g][k] ----
// W1 k-order CHANGED: k 0..255 = Wh1 (h1 terms first), 256..331 = Wi1, 332..351 zero
__global__ void repack_kernel(const float* __restrict__ Wi1, const float* __restrict__ Wh1,
                              const float* __restrict__ Wi2, const float* __restrict__ Wh2,
                              u16* __restrict__ w1hg, u16* __restrict__ w1lg,
                              u16* __restrict__ w2hg, u16* __restrict__ w2lg) {
  int idx = blockIdx.x * blockDim.x + threadIdx.x;
  const int N1 = 1024 * K1;
  if (idx < N1) {
    int c = idx / K1, k = idx - c * K1;
    int src = (c & 3) * HH + (c >> 2);
    float v = 0.f;
    if (k < HH) v = Wh1[k * 1024 + src];
    else if (k < HH + DD) v = Wi1[(k - HH) * 1024 + src];
    u16 h, l; split2(v, h, l);
    w1hg[idx] = h; w1lg[idx] = l;
  } else if (idx < N1 + 1024 * K2) {
    int d = idx - N1;
    int c = d >> 9, k = d & 511;
    int src = (c & 3) * HH + (c >> 2);
    float v = (k < HH) ? Wi2[k * 1024 + src] : Wh2[(k - HH) * 1024 + src];
    u16 h, l; split2(v, h, l);
    w2hg[d] = h; w2lg[d] = l;
  }
}

// 3-term split-fp32 MFMA over one K-chunk, both 16-col tiles of this wave
#define MFMA3(AA, AB, AC, AH, AL, BH, BL)                                   \
  { (AA) = __builtin_amdgcn_mfma_f32_16x16x32_bf16(AH, BH, (AA), 0, 0, 0);  \
    (AB) = __builtin_amdgcn_mfma_f32_16x16x32_bf16(AH, BL, (AB), 0, 0, 0);  \
    (AC) = __builtin_amdgcn_mfma_f32_16x16x32_bf16(AL, BH, (AC), 0, 0, 0); }

#define MFMA_CH(AH, AL, PH0, PL0, PH1, PL1, KOFF)                           \
  { bf16x8 b0h_ = *(const bf16x8*)((PH0) + (KOFF));                         \
    bf16x8 b0l_ = *(const bf16x8*)((PL0) + (KOFF));                         \
    bf16x8 b1h_ = *(const bf16x8*)((PH1) + (KOFF));                         \
    bf16x8 b1l_ = *(const bf16x8*)((PL1) + (KOFF));                         \
    MFMA3(aA0, aB0, aC0, AH, AL, b0h_, b0l_)                                \
    MFMA3(aA1, aB1, aC1, AH, AL, b1h_, b1l_) }

// de-redundified gates: each lane computes ONE activation, exchanges via shfl_xor.
// at gi==0: i = a_, f = v1_, g = v2_, o = v3_  (others compute garbage, never stored)
#define GATES(Z, CS, DW)                                                    \
  _Pragma("unroll")                                                         \
  for (int r = 0; r < 4; ++r) {                                             \
    float a_ = gact((Z)[r], gi == 2);                                       \
    float v1_ = __shfl_xor(a_, 1);                                          \
    float v2_ = __shfl_xor(a_, 2);                                          \
    float v3_ = __shfl_xor(a_, 3);                                          \
    float cn_ = v1_ * (CS)[r] + a_ * v2_;                                   \
    (CS)[r] = cn_;                                                          \
    float hv_ = v3_ * tanh_f(cn_);                                          \
    if (gi == 0) {                                                          \
      u16 hh_, hl_; split2(hv_, hh_, hl_);                                  \
      ast1((DW) + (size_t)(rbase + r) * HH + jg, (u32)hh_ | ((u32)hl_ << 16)); \
    }                                                                       \
  }

__global__ __launch_bounds__(NTHREADS, 2) void lstm_kernel(
    const float* __restrict__ x,
    const float* __restrict__ b1, const float* __restrict__ b2,
    const float* __restrict__ Wd, const float* __restrict__ bd,
    const u16* __restrict__ w1hg, const u16* __restrict__ w1lg,
    const u16* __restrict__ w2hg, const u16* __restrict__ w2lg,
    u32* __restrict__ h1w, u32* __restrict__ h2w,
    u32* __restrict__ flags,
    float* __restrict__ out)
{
  __shared__ u16 w1h[32 * WS1], w1l[32 * WS1];     // 46,080 B
  __shared__ u16 w2h[32 * WS2], w2l[32 * WS2];     // 66,560 B
  __shared__ float zx[2][8][64][4];                // 16,384 B (z exchange, 2 phase bufs)

  const int tid = threadIdx.x;
  const int lane = tid & 63;
  const int wv = tid >> 6;            // 0..7
  const int m  = wv & 3;              // row-group: rows m*16..m*16+15
  const int kh = wv >> 2;             // K-half (0/1); also this wave's gate tile
  const int nl = lane & 15;
  const int qd = lane >> 4;           // 0..3
  const int bt = blockIdx.x & 7;      // row-group (XCD-aligned via %8 dispatch heuristic)
  const int jt = blockIdx.x >> 3;     // 0..31 col-group
  const int row0 = bt * 64;

  u32* gAp = flags + bt * 1024;
  u32* gBp = flags + 8192 + bt * 1024;
  u32* gAslot = gAp + jt * 32;
  u32* gBslot = gBp + jt * 32;

  // ---- stage weight slices to LDS once ----
  for (int i = tid; i < 32 * (K1 / 2); i += NTHREADS) {
    int c = i / 176, kk = i - c * 176;
    ((u32*)&w1h[c * WS1])[kk] = ((const u32*)(w1hg + (size_t)(jt * 32 + c) * K1))[kk];
    ((u32*)&w1l[c * WS1])[kk] = ((const u32*)(w1lg + (size_t)(jt * 32 + c) * K1))[kk];
  }
  for (int i = tid; i < 32 * (K2 / 2); i += NTHREADS) {
    int c = i >> 8, kk = i & 255;
    ((u32*)&w2h[c * WS2])[kk] = ((const u32*)(w2hg + (size_t)(jt * 32 + c) * K2))[kk];
    ((u32*)&w2l[c * WS2])[kk] = ((const u32*)(w2lg + (size_t)(jt * 32 + c) * K2))[kk];
  }

  // gate-phase constants (this wave gates tile kh)
  const int cg_col = jt * 32 + kh * 16 + nl;
  const int jg = cg_col >> 2;
  const int gi = cg_col & 3;
  const int rbase = row0 + m * 16 + qd * 4;

  // acc-init biases per tile; counted once (kh==0 only)
  float ab1[2], ab2[2];
#pragma unroll
  for (int tl = 0; tl < 2; ++tl) {
    int col = jt * 32 + tl * 16 + nl;
    float v1 = b1[(col & 3) * HH + (col >> 2)];
    float v2 = b2[(col & 3) * HH + (col >> 2)];
    ab1[tl] = (kh == 0) ? v1 : 0.f;
    ab2[tl] = (kh == 0) ? v2 : 0.f;
  }

  const int arow = row0 + m * 16 + nl;   // A-fragment row for this lane

  const u16* pB1h0 = w1h + nl * WS1;
  const u16* pB1l0 = w1l + nl * WS1;
  const u16* pB1h1 = w1h + (16 + nl) * WS1;
  const u16* pB1l1 = w1l + (16 + nl) * WS1;
  const u16* pB2h0 = w2h + nl * WS2;
  const u16* pB2l0 = w2l + nl * WS2;
  const u16* pB2h1 = w2h + (16 + nl) * WS2;
  const u16* pB2l1 = w2l + (16 + nl) * WS2;

  float cs1[4] = {0.f, 0.f, 0.f, 0.f}, cs2[4] = {0.f, 0.f, 0.f, 0.f};
  bf16x8 h1fh[4], h1fl[4];   // this wave's K-half of h1[t] fragments (reg-reused L2->L1)

  __syncthreads();   // weights staged

  // ---- prologue: h1[0] = gates(b1 + x[0]@Wi1) -> slot 0; post A=1, B=1 ----
  {
    f32x4 aA0 = {ab1[0], ab1[0], ab1[0], ab1[0]};
    f32x4 aA1 = {ab1[1], ab1[1], ab1[1], ab1[1]};
    f32x4 aB0 = {0,0,0,0}, aB1 = {0,0,0,0}, aC0 = {0,0,0,0}, aC1 = {0,0,0,0};
    const float* xrow = x + (size_t)arow * TT * DD;
    if (kh == 0) {
#pragma unroll
      for (int ci = 0; ci < 2; ++ci) {
        float xv[8];
        float4 f0 = *(const float4*)(xrow + ci * 32 + qd * 8);
        float4 f1 = *(const float4*)(xrow + ci * 32 + qd * 8 + 4);
        xv[0]=f0.x; xv[1]=f0.y; xv[2]=f0.z; xv[3]=f0.w;
        xv[4]=f1.x; xv[5]=f1.y; xv[6]=f1.z; xv[7]=f1.w;
        bf16x8 xh, xl; splitv8(xv, xh, xl);
        const int koff = (8 + ci) * 32 + qd * 8;
        MFMA_CH(xh, xl, pB1h0, pB1l0, pB1h1, pB1l1, koff)
      }
    } else {
      float xv[8] = {0,0,0,0,0,0,0,0};
      if (qd == 0) {
        float4 f0 = *(const float4*)(xrow + 64);
        float4 f1 = *(const float4*)(xrow + 68);
        xv[0]=f0.x; xv[1]=f0.y; xv[2]=f0.z; xv[3]=f0.w;
        xv[4]=f1.x; xv[5]=f1.y; xv[6]=f1.z; xv[7]=f1.w;
      } else if (qd == 1) {
        float4 f0 = *(const float4*)(xrow + 72);
        xv[0]=f0.x; xv[1]=f0.y; xv[2]=f0.z; xv[3]=f0.w;
      }
      bf16x8 xh, xl; splitv8(xv, xh, xl);
      const int koff = 10 * 32 + qd * 8;
      MFMA_CH(xh, xl, pB1h0, pB1l0, pB1h1, pB1l1, koff)
    }
    f32x4 zk = (kh == 0) ? (aA0 + aB0 + aC0) : (aA1 + aB1 + aC1);
    f32x4 zo = (kh == 0) ? (aA1 + aB1 + aC1) : (aA0 + aB0 + aC0);
    *(f32x4*)&zx[1][wv][lane][0] = zo;
    __syncthreads();
    zk += *(const f32x4*)&zx[1][wv ^ 4][lane][0];
    GATES(zk, cs1, h1w)
    __syncthreads();   // h1[0] stores drained
    if (tid == 0) { ast1(gAslot, 1u); ast1(gBslot, 1u); }
  }

  // ---- main loop: L2[t] then L1[t+1] ----
#pragma unroll 1
  for (int t = 0; t < TT; ++t) {
    const u32* h1cw = h1w + (t & 1) * BBHH;        // h1[t]
    u32* h1nw = h1w + ((t + 1) & 1) * BBHH;        // h1[t+1]
    const u32* h2pw = h2w + ((t + 1) & 1) * BBHH;  // h2[t-1]
    u32* h2cw = h2w + (t & 1) * BBHH;              // h2[t]

    // ----- L2[t]: z2 = b2 + h1[t]@Wi2 + h2[t-1]@Wh2 -----
    {
      f32x4 aA0 = {ab2[0], ab2[0], ab2[0], ab2[0]};
      f32x4 aA1 = {ab2[1], ab2[1], ab2[1], ab2[1]};
      f32x4 aB0 = {0,0,0,0}, aB1 = {0,0,0,0}, aC0 = {0,0,0,0}, aC1 = {0,0,0,0};

      wait_flags(gAp, t + 1);                       // h2[t-1] ready; h2[t] slot write-safe
      u64 rw2[4][4];
      if (t > 0) {
        const u32* hp = h2pw + (size_t)arow * HH + kh * 128;
#pragma unroll
        for (int i = 0; i < 4; ++i) {
          const u32* p = hp + i * 32 + qd * 8;
          rw2[i][0] = ald2(p);     rw2[i][1] = ald2(p + 2);
          rw2[i][2] = ald2(p + 4); rw2[i][3] = ald2(p + 6);
        }
      }
      wait_flags(gBp, t + 1);                       // h1[t] ready
      u64 rw1[4][4];
      {
        const u32* hp = h1cw + (size_t)arow * HH + kh * 128;
#pragma unroll
        for (int i = 0; i < 4; ++i) {
          const u32* p = hp + i * 32 + qd * 8;
          rw1[i][0] = ald2(p);     rw1[i][1] = ald2(p + 2);
          rw1[i][2] = ald2(p + 4); rw1[i][3] = ald2(p + 6);
        }
      }
      if (t > 0) {
#pragma unroll
        for (int i = 0; i < 4; ++i) {
          bf16x8 ah = hi8(rw2[i]), al = lo8(rw2[i]);
          const int koff = (8 + kh * 4 + i) * 32 + qd * 8;
          MFMA_CH(ah, al, pB2h0, pB2l0, pB2h1, pB2l1, koff)
        }
      }
#pragma unroll
      for (int i = 0; i < 4; ++i) {
        h1fh[i] = hi8(rw1[i]); h1fl[i] = lo8(rw1[i]);
        const int koff = (kh * 4 + i) * 32 + qd * 8;
        MFMA_CH(h1fh[i], h1fl[i], pB2h0, pB2l0, pB2h1, pB2l1, koff)
      }
      f32x4 zk = (kh == 0) ? (aA0 + aB0 + aC0) : (aA1 + aB1 + aC1);
      f32x4 zo = (kh == 0) ? (aA1 + aB1 + aC1) : (aA0 + aB0 + aC0);
      *(f32x4*)&zx[0][wv][lane][0] = zo;
      __syncthreads();
      zk += *(const f32x4*)&zx[0][wv ^ 4][lane][0];
      GATES(zk, cs2, h2cw)
      post_flag(gAslot, t + 2);
    }

    // ----- L1[t+1]: z1 = b1 + h1[t]@Wh1 (regs!) + x[t+1]@Wi1 -----
    if (t < TT - 1) {
      f32x4 aA0 = {ab1[0], ab1[0], ab1[0], ab1[0]};
      f32x4 aA1 = {ab1[1], ab1[1], ab1[1], ab1[1]};
      f32x4 aB0 = {0,0,0,0}, aB1 = {0,0,0,0}, aC0 = {0,0,0,0}, aC1 = {0,0,0,0};
      const float* xrow = x + ((size_t)arow * TT + (t + 1)) * DD;

      if (kh == 0) {
#pragma unroll
        for (int ci = 0; ci < 2; ++ci) {
          float xv[8];
          float4 f0 = *(const float4*)(xrow + ci * 32 + qd * 8);
          float4 f1 = *(const float4*)(xrow + ci * 32 + qd * 8 + 4);
          xv[0]=f0.x; xv[1]=f0.y; xv[2]=f0.z; xv[3]=f0.w;
          xv[4]=f1.x; xv[5]=f1.y; xv[6]=f1.z; xv[7]=f1.w;
          bf16x8 xh, xl; splitv8(xv, xh, xl);
          const int koff = (8 + ci) * 32 + qd * 8;
          MFMA_CH(xh, xl, pB1h0, pB1l0, pB1h1, pB1l1, koff)
        }
      } else {
        float xv[8] = {0,0,0,0,0,0,0,0};
        if (qd == 0) {
          float4 f0 = *(const float4*)(xrow + 64);
          float4 f1 = *(const float4*)(xrow + 68);
          xv[0]=f0.x; xv[1]=f0.y; xv[2]=f0.z; xv[3]=f0.w;
          xv[4]=f1.x; xv[5]=f1.y; xv[6]=f1.z; xv[7]=f1.w;
        } else if (qd == 1) {
          float4 f0 = *(const float4*)(xrow + 72);
          xv[0]=f0.x; xv[1]=f0.y; xv[2]=f0.z; xv[3]=f0.w;
        }
        bf16x8 xh, xl; splitv8(xv, xh, xl);
        const int koff = 10 * 32 + qd * 8;
        MFMA_CH(xh, xl, pB1h0, pB1l0, pB1h1, pB1l1, koff)
      }
      // h1[t] terms from registers (loaded during L2[t])
#pragma unroll
      for (int i = 0; i < 4; ++i) {
        const int koff = (kh * 4 + i) * 32 + qd * 8;
        MFMA_CH(h1fh[i], h1fl[i], pB1h0, pB1l0, pB1h1, pB1l1, koff)
      }
      f32x4 zk = (kh == 0) ? (aA0 + aB0 + aC0) : (aA1 + aB1 + aC1);
      f32x4 zo = (kh == 0) ? (aA1 + aB1 + aC1) : (aA0 + aB0 + aC0);
      *(f32x4*)&zx[1][wv][lane][0] = zo;
      __syncthreads();
      zk += *(const f32x4*)&zx[1][wv ^ 4][lane][0];
      GATES(zk, cs1, h1nw)
      post_flag(gBslot, t + 2);
    }
  }

  // ---- dense head: logits = h2[511] @ Wd + bd (slot 1) ----
  wait_flags(gAp, TT + 1);
  if (tid < 2 * NC) {
    int r = row0 + jt * 2 + tid / NC;
    int n = tid - (tid / NC) * NC;
    float s = bd[n];
    const u32* fw = h2w + BBHH + (size_t)r * HH;
#pragma unroll 8
    for (int k = 0; k < HH; ++k) {
      u32 w = ald1(fw + k);
      s += (bf2f((u16)w) + bf2f((u16)(w >> 16))) * Wd[k * NC + n];
    }
    out[r * NC + n] = s;
  }
}

extern "C" void kernel_launch(void* const* d_in, const int* in_sizes, int n_in,
                              void* d_out, int out_size, void* d_ws, size_t ws_size,
                              hipStream_t stream) {
  const float* x   = (const float*)d_in[0];
  const float* Wi1 = (const float*)d_in[1];
  const float* Wh1 = (const float*)d_in[2];
  const float* b1  = (const float*)d_in[3];
  const float* Wi2 = (const float*)d_in[4];
  const float* Wh2 = (const float*)d_in[5];
  const float* b2  = (const float*)d_in[6];
  const float* Wd  = (const float*)d_in[7];
  const float* bd  = (const float*)d_in[8];

  char* ws = (char*)d_ws;
  // ws layout (bytes):
  //   [0, 1M)          h1w ping-pong u32 words (hi|lo<<16) [2][512][256]
  //   [1M, 2M)         h2w
  //   [2M, ..)         w1hg/w1lg (720,896 each), w2hg/w2lg (1,048,576 each)
  //   [5,636,096, +64K) flag arrays A and B (zeroed every call)
  u32* h1w = (u32*)(ws);
  u32* h2w = (u32*)(ws + 1048576u);
  u16* w1hg = (u16*)(ws + 2097152u);
  u16* w1lg = (u16*)(ws + 2097152u + 720896u);
  u16* w2hg = (u16*)(ws + 2097152u + 2u * 720896u);
  u16* w2lg = (u16*)(ws + 2097152u + 2u * 720896u + 1048576u);
  u32* flags = (u32*)(ws + 5636096u);
  float* out = (float*)d_out;

  hipMemsetAsync((void*)flags, 0, 65536, stream);
  const int total = 1024 * K1 + 1024 * K2;
  repack_kernel<<<(total + 255) / 256, 256, 0, stream>>>(
      Wi1, Wh1, Wi2, Wh2, w1hg, w1lg, w2hg, w2lg);

  void* args[] = {
    (void*)&x, (void*)&b1, (void*)&b2, (void*)&Wd, (void*)&bd,
    (void*)&w1hg, (void*)&w1lg, (void*)&w2hg, (void*)&w2lg,
    (void*)&h1w, (void*)&h2w,
    (void*)&flags, (void*)&out
  };
  // Cooperative launch purely for the co-residency guarantee; sync is custom.
  (void)hipLaunchCooperativeKernel((void*)lstm_kernel, dim3(NBLK),
                                   dim3(NTHREADS), args, 0, stream);
}

// Round 4
// 5652.970 us; speedup vs baseline: 9.1163x; 1.0170x over previous
//
#include <hip/hip_runtime.h>

#define BB 512
#define TT 512
#define DD 76
#define HH 256
#define NC 25
#define NBLK 256
#define NTHREADS 512
#define BBHH (BB * HH)   // u32 words per h slot

#define K1 352      // L1 virtual K: 256 h1 | 76 x | 20 zero-pad (h1 first)
#define K2 512      // L2 K: 256 h1 | 256 h2
#define WS1 360     // LDS k-stride (u16) for W1 planes
#define WS2 520     // LDS k-stride (u16) for W2 planes

typedef unsigned short u16;
typedef unsigned int u32;
typedef unsigned long long u64;
typedef __attribute__((ext_vector_type(8))) short bf16x8;
typedef __attribute__((ext_vector_type(4))) float f32x4;

__device__ __forceinline__ float bf2f(u16 v) {
  union { u32 u; float f; } c; c.u = ((u32)v) << 16; return c.f;
}
__device__ __forceinline__ u16 f2bf(float f) {
  union { u32 u; float f; } c; c.f = f;
  u32 r = c.u + 0x7FFFu + ((c.u >> 16) & 1u);   // RNE
  return (u16)(r >> 16);
}
__device__ __forceinline__ void split2(float f, u16& h, u16& l) {
  u16 hh = f2bf(f);
  float r = f - bf2f(hh);
  h = hh; l = f2bf(r);
}
__device__ __forceinline__ float tanh_f(float v) {
  float e = __expf(2.0f * v);
  return 1.0f - 2.0f / (e + 1.0f);
}
__device__ __forceinline__ float gact(float v, bool is_tanh) {
  float e = __expf(is_tanh ? 2.0f * v : -v);
  float inv = 1.0f / (1.0f + e);
  return is_tanh ? 1.0f - 2.0f * inv : inv;
}

// ---- coherence-point (IF$) transport: relaxed agent atomics, NO fences ----
__device__ __forceinline__ u64 ald2(const u32* p) {
  return __hip_atomic_load((const u64*)p, __ATOMIC_RELAXED, __HIP_MEMORY_SCOPE_AGENT);
}
__device__ __forceinline__ u32 ald1(const u32* p) {
  return __hip_atomic_load(p, __ATOMIC_RELAXED, __HIP_MEMORY_SCOPE_AGENT);
}
__device__ __forceinline__ void ast1(u32* p, u32 v) {
  __hip_atomic_store(p, v, __ATOMIC_RELAXED, __HIP_MEMORY_SCOPE_AGENT);
}
__device__ __forceinline__ void ast2(u64* p, u64 v) {
  __hip_atomic_store(p, v, __ATOMIC_RELAXED, __HIP_MEMORY_SCOPE_AGENT);
}

// ---- distributed flag sync: 32 flags/group, each on own 128B line ----
__device__ __forceinline__ void wait_flags(const u32* fbase, u32 target) {
  const int tid = threadIdx.x;
  if (tid < 32) {
    const u32* p = fbase + tid * 32;
    while (__hip_atomic_load(p, __ATOMIC_RELAXED, __HIP_MEMORY_SCOPE_AGENT) < target)
      __builtin_amdgcn_s_sleep(1);
  }
  __syncthreads();   // execution-orders subsequent h loads after the poll
}
__device__ __forceinline__ void post_flag(u32* slot, u32 val) {
  __syncthreads();   // all waves' h-stores vmcnt-drained (at coherence point)
  if (threadIdx.x == 0) ast1(slot, val);
}

// packed h word: low16 = bf16-hi part, high16 = bf16-lo part
__device__ __forceinline__ bf16x8 hi8(const u64 w[4]) {
  union { u32 u[4]; bf16x8 v; } c;
#pragma unroll
  for (int i = 0; i < 4; ++i)
    c.u[i] = __builtin_amdgcn_perm((u32)(w[i] >> 32), (u32)w[i], 0x05040100u);
  return c.v;
}
__device__ __forceinline__ bf16x8 lo8(const u64 w[4]) {
  union { u32 u[4]; bf16x8 v; } c;
#pragma unroll
  for (int i = 0; i < 4; ++i)
    c.u[i] = __builtin_amdgcn_perm((u32)(w[i] >> 32), (u32)w[i], 0x07060302u);
  return c.v;
}

__device__ __forceinline__ void splitv8(const float* f, bf16x8& vh, bf16x8& vl) {
  union { u16 s[8]; bf16x8 v; } ch, cl;
#pragma unroll
  for (int i = 0; i < 8; ++i) { u16 h_, l_; split2(f[i], h_, l_); ch.s[i] = h_; cl.s[i] = l_; }
  vh = ch.v; vl = cl.v;
}

// ---- repack: fp32 [k][4H] -> hi/lo bf16 planes, layout [c=4j+g][k] ----
// W1 k-order: k 0..255 = Wh1 (h1 terms first), 256..331 = Wi1, 332..351 zero
__global__ void repack_kernel(const float* __restrict__ Wi1, const float* __restrict__ Wh1,
                              const float* __restrict__ Wi2, const float* __restrict__ Wh2,
                              u16* __restrict__ w1hg, u16* __restrict__ w1lg,
                              u16* __restrict__ w2hg, u16* __restrict__ w2lg) {
  int idx = blockIdx.x * blockDim.x + threadIdx.x;
  const int N1 = 1024 * K1;
  if (idx < N1) {
    int c = idx / K1, k = idx - c * K1;
    int src = (c & 3) * HH + (c >> 2);
    float v = 0.f;
    if (k < HH) v = Wh1[k * 1024 + src];
    else if (k < HH + DD) v = Wi1[(k - HH) * 1024 + src];
    u16 h, l; split2(v, h, l);
    w1hg[idx] = h; w1lg[idx] = l;
  } else if (idx < N1 + 1024 * K2) {
    int d = idx - N1;
    int c = d >> 9, k = d & 511;
    int src = (c & 3) * HH + (c >> 2);
    float v = (k < HH) ? Wi2[k * 1024 + src] : Wh2[(k - HH) * 1024 + src];
    u16 h, l; split2(v, h, l);
    w2hg[d] = h; w2lg[d] = l;
  }
}

// 3-term split-fp32 MFMA over one K-chunk, both 16-col tiles of this wave
#define MFMA3(AA, AB, AC, AH, AL, BH, BL)                                   \
  { (AA) = __builtin_amdgcn_mfma_f32_16x16x32_bf16(AH, BH, (AA), 0, 0, 0);  \
    (AB) = __builtin_amdgcn_mfma_f32_16x16x32_bf16(AH, BL, (AB), 0, 0, 0);  \
    (AC) = __builtin_amdgcn_mfma_f32_16x16x32_bf16(AL, BH, (AC), 0, 0, 0); }

#define MFMA_CH(AH, AL, PH0, PL0, PH1, PL1, KOFF)                           \
  { bf16x8 b0h_ = *(const bf16x8*)((PH0) + (KOFF));                         \
    bf16x8 b0l_ = *(const bf16x8*)((PL0) + (KOFF));                         \
    bf16x8 b1h_ = *(const bf16x8*)((PH1) + (KOFF));                         \
    bf16x8 b1l_ = *(const bf16x8*)((PL1) + (KOFF));                         \
    MFMA3(aA0, aB0, aC0, AH, AL, b0h_, b0l_)                                \
    MFMA3(aA1, aB1, aC1, AH, AL, b1h_, b1l_) }

// de-redundified gates + coalesced store: each lane computes ONE activation,
// exchanges via shfl_xor; then gathers 4 unit-words per row into lane nl==0
// which issues 2 contiguous u64 agent stores (16B per row, was 4 scattered u32).
#define GATES_ST(Z, CS, DST)                                                \
  { u32 hwv[4];                                                             \
    _Pragma("unroll")                                                       \
    for (int r = 0; r < 4; ++r) {                                           \
      float a_ = gact((Z)[r], gi == 2);                                     \
      float v1_ = __shfl_xor(a_, 1);                                        \
      float v2_ = __shfl_xor(a_, 2);                                        \
      float v3_ = __shfl_xor(a_, 3);                                        \
      float cn_ = v1_ * (CS)[r] + a_ * v2_;                                 \
      (CS)[r] = cn_;                                                        \
      float hv_ = v3_ * tanh_f(cn_);                                        \
      u16 hh_, hl_; split2(hv_, hh_, hl_);                                  \
      hwv[r] = (u32)hh_ | ((u32)hl_ << 16);                                 \
    }                                                                       \
    _Pragma("unroll")                                                       \
    for (int r = 0; r < 4; ++r) {                                           \
      int base_ = lane & 48;                                                \
      u32 w1_ = __shfl(hwv[r], base_ + 4);                                  \
      u32 w2_ = __shfl(hwv[r], base_ + 8);                                  \
      u32 w3_ = __shfl(hwv[r], base_ + 12);                                 \
      if (nl == 0) {                                                        \
        u64* dp_ = (u64*)((DST) + (size_t)(rbase + r) * HH + jt * 8 + kh * 4); \
        ast2(dp_,     (u64)hwv[r] | ((u64)w1_ << 32));                      \
        ast2(dp_ + 1, (u64)w2_    | ((u64)w3_ << 32));                      \
      }                                                                     \
    }                                                                       \
  }

// issue 4-chunk packed-h loads for this wave's K-half into RW
#define LOAD_RW(RW, BASEPTR)                                                \
  { const u32* hp_ = (BASEPTR) + (size_t)arow * HH + kh * 128;              \
    _Pragma("unroll")                                                       \
    for (int i_ = 0; i_ < 4; ++i_) {                                        \
      const u32* p_ = hp_ + i_ * 32 + qd * 8;                               \
      (RW)[i_][0] = ald2(p_);     (RW)[i_][1] = ald2(p_ + 2);               \
      (RW)[i_][2] = ald2(p_ + 4); (RW)[i_][3] = ald2(p_ + 6);               \
    } }

__global__ __launch_bounds__(NTHREADS, 2) void lstm_kernel(
    const float* __restrict__ x,
    const float* __restrict__ b1, const float* __restrict__ b2,
    const float* __restrict__ Wd, const float* __restrict__ bd,
    const u16* __restrict__ w1hg, const u16* __restrict__ w1lg,
    const u16* __restrict__ w2hg, const u16* __restrict__ w2lg,
    u32* __restrict__ h1w, u32* __restrict__ h2w,
    u32* __restrict__ flags,
    float* __restrict__ out)
{
  __shared__ u16 w1h[32 * WS1], w1l[32 * WS1];     // 46,080 B
  __shared__ u16 w2h[32 * WS2], w2l[32 * WS2];     // 66,560 B
  __shared__ float zx[2][8][64][4];                // 16,384 B (z exchange)

  const int tid = threadIdx.x;
  const int lane = tid & 63;
  const int wv = tid >> 6;            // 0..7
  const int m  = wv & 3;              // row-group: rows m*16..m*16+15
  const int kh = wv >> 2;             // K-half (0/1); also this wave's gate tile
  const int nl = lane & 15;
  const int qd = lane >> 4;           // 0..3
  const int bt = blockIdx.x & 7;      // row-group (XCD-aligned via %8 dispatch heuristic)
  const int jt = blockIdx.x >> 3;     // 0..31 col-group
  const int row0 = bt * 64;

  u32* gAp = flags + bt * 1024;
  u32* gBp = flags + 8192 + bt * 1024;
  u32* gAslot = gAp + jt * 32;
  u32* gBslot = gBp + jt * 32;

  // ---- stage weight slices to LDS once ----
  for (int i = tid; i < 32 * (K1 / 2); i += NTHREADS) {
    int c = i / 176, kk = i - c * 176;
    ((u32*)&w1h[c * WS1])[kk] = ((const u32*)(w1hg + (size_t)(jt * 32 + c) * K1))[kk];
    ((u32*)&w1l[c * WS1])[kk] = ((const u32*)(w1lg + (size_t)(jt * 32 + c) * K1))[kk];
  }
  for (int i = tid; i < 32 * (K2 / 2); i += NTHREADS) {
    int c = i >> 8, kk = i & 255;
    ((u32*)&w2h[c * WS2])[kk] = ((const u32*)(w2hg + (size_t)(jt * 32 + c) * K2))[kk];
    ((u32*)&w2l[c * WS2])[kk] = ((const u32*)(w2lg + (size_t)(jt * 32 + c) * K2))[kk];
  }

  // gate-phase constants (this wave gates tile kh)
  const int cg_col = jt * 32 + kh * 16 + nl;
  const int gi = cg_col & 3;
  const int rbase = row0 + m * 16 + qd * 4;

  // acc-init biases per tile; counted once (kh==0 only)
  float ab1[2], ab2[2];
#pragma unroll
  for (int tl = 0; tl < 2; ++tl) {
    int col = jt * 32 + tl * 16 + nl;
    float v1 = b1[(col & 3) * HH + (col >> 2)];
    float v2 = b2[(col & 3) * HH + (col >> 2)];
    ab1[tl] = (kh == 0) ? v1 : 0.f;
    ab2[tl] = (kh == 0) ? v2 : 0.f;
  }

  const int arow = row0 + m * 16 + nl;   // A-fragment row for this lane

  const u16* pB1h0 = w1h + nl * WS1;
  const u16* pB1l0 = w1l + nl * WS1;
  const u16* pB1h1 = w1h + (16 + nl) * WS1;
  const u16* pB1l1 = w1l + (16 + nl) * WS1;
  const u16* pB2h0 = w2h + nl * WS2;
  const u16* pB2l0 = w2l + nl * WS2;
  const u16* pB2h1 = w2h + (16 + nl) * WS2;
  const u16* pB2l1 = w2l + (16 + nl) * WS2;

  float cs1[4] = {0.f, 0.f, 0.f, 0.f}, cs2[4] = {0.f, 0.f, 0.f, 0.f};
  u64 rwh1[4][4];            // raw packed h1 words (loaded in B, permed in next A)
  bf16x8 h1fh[4], h1fl[4];   // this wave's K-half of h1[t] fragments

  __syncthreads();   // weights staged

  // ---- prologue: h1[0] = gates(b1 + x[0]@Wi1) -> slot 0; post A=1, B=1 ----
  {
    f32x4 aA0 = {ab1[0], ab1[0], ab1[0], ab1[0]};
    f32x4 aA1 = {ab1[1], ab1[1], ab1[1], ab1[1]};
    f32x4 aB0 = {0,0,0,0}, aB1 = {0,0,0,0}, aC0 = {0,0,0,0}, aC1 = {0,0,0,0};
    const float* xrow = x + (size_t)arow * TT * DD;
    if (kh == 0) {
#pragma unroll
      for (int ci = 0; ci < 2; ++ci) {
        float xv[8];
        float4 f0 = *(const float4*)(xrow + ci * 32 + qd * 8);
        float4 f1 = *(const float4*)(xrow + ci * 32 + qd * 8 + 4);
        xv[0]=f0.x; xv[1]=f0.y; xv[2]=f0.z; xv[3]=f0.w;
        xv[4]=f1.x; xv[5]=f1.y; xv[6]=f1.z; xv[7]=f1.w;
        bf16x8 xh, xl; splitv8(xv, xh, xl);
        const int koff = (8 + ci) * 32 + qd * 8;
        MFMA_CH(xh, xl, pB1h0, pB1l0, pB1h1, pB1l1, koff)
      }
    } else {
      float xv[8] = {0,0,0,0,0,0,0,0};
      if (qd == 0) {
        float4 f0 = *(const float4*)(xrow + 64);
        float4 f1 = *(const float4*)(xrow + 68);
        xv[0]=f0.x; xv[1]=f0.y; xv[2]=f0.z; xv[3]=f0.w;
        xv[4]=f1.x; xv[5]=f1.y; xv[6]=f1.z; xv[7]=f1.w;
      } else if (qd == 1) {
        float4 f0 = *(const float4*)(xrow + 72);
        xv[0]=f0.x; xv[1]=f0.y; xv[2]=f0.z; xv[3]=f0.w;
      }
      bf16x8 xh, xl; splitv8(xv, xh, xl);
      const int koff = 10 * 32 + qd * 8;
      MFMA_CH(xh, xl, pB1h0, pB1l0, pB1h1, pB1l1, koff)
    }
    f32x4 zk = (kh == 0) ? (aA0 + aB0 + aC0) : (aA1 + aB1 + aC1);
    f32x4 zo = (kh == 0) ? (aA1 + aB1 + aC1) : (aA0 + aB0 + aC0);
    *(f32x4*)&zx[1][wv][lane][0] = zo;
    __syncthreads();
    zk += *(const f32x4*)&zx[1][wv ^ 4][lane][0];
    GATES_ST(zk, cs1, h1w)
    __syncthreads();   // h1[0] stores drained
    if (tid == 0) { ast1(gAslot, 1u); ast1(gBslot, 1u); }
    wait_flags(gBp, 1);          // h1[0] fully published
    LOAD_RW(rwh1, h1w)           // h1[0] raw words -> regs
  }

  // ---- main loop: A = L1[t+1] (local), then B = L2[t] ----
#pragma unroll 1
  for (int t = 0; t < TT; ++t) {
    u32* h1nw = h1w + ((t + 1) & 1) * BBHH;        // h1[t+1]
    const u32* h2pw = h2w + ((t + 1) & 1) * BBHH;  // h2[t-1]
    u32* h2cw = h2w + (t & 1) * BBHH;              // h2[t]

    // perm raw h1[t] words (loaded last B / prologue) into MFMA fragments
#pragma unroll
    for (int i = 0; i < 4; ++i) { h1fh[i] = hi8(rwh1[i]); h1fl[i] = lo8(rwh1[i]); }

    // ----- A: L1[t+1] = gates(b1 + h1[t]@Wh1 (regs) + x[t+1]@Wi1) -----
    if (t < TT - 1) {
      f32x4 aA0 = {ab1[0], ab1[0], ab1[0], ab1[0]};
      f32x4 aA1 = {ab1[1], ab1[1], ab1[1], ab1[1]};
      f32x4 aB0 = {0,0,0,0}, aB1 = {0,0,0,0}, aC0 = {0,0,0,0}, aC1 = {0,0,0,0};
      const float* xrow = x + ((size_t)arow * TT + (t + 1)) * DD;

      // issue x loads early; consume after the h1-register MFMAs
      float4 xf0, xf1, xf2, xf3;
      if (kh == 0) {
        xf0 = *(const float4*)(xrow + qd * 8);
        xf1 = *(const float4*)(xrow + qd * 8 + 4);
        xf2 = *(const float4*)(xrow + 32 + qd * 8);
        xf3 = *(const float4*)(xrow + 32 + qd * 8 + 4);
      } else {
        xf0 = make_float4(0,0,0,0); xf1 = make_float4(0,0,0,0);
        if (qd == 0) {
          xf0 = *(const float4*)(xrow + 64);
          xf1 = *(const float4*)(xrow + 68);
        } else if (qd == 1) {
          xf0 = *(const float4*)(xrow + 72);
        }
      }

      // h1[t] terms from registers
#pragma unroll
      for (int i = 0; i < 4; ++i) {
        const int koff = (kh * 4 + i) * 32 + qd * 8;
        MFMA_CH(h1fh[i], h1fl[i], pB1h0, pB1l0, pB1h1, pB1l1, koff)
      }
      // x terms
      if (kh == 0) {
        float xv[8];
        xv[0]=xf0.x; xv[1]=xf0.y; xv[2]=xf0.z; xv[3]=xf0.w;
        xv[4]=xf1.x; xv[5]=xf1.y; xv[6]=xf1.z; xv[7]=xf1.w;
        bf16x8 xh, xl; splitv8(xv, xh, xl);
        MFMA_CH(xh, xl, pB1h0, pB1l0, pB1h1, pB1l1, 8 * 32 + qd * 8)
        xv[0]=xf2.x; xv[1]=xf2.y; xv[2]=xf2.z; xv[3]=xf2.w;
        xv[4]=xf3.x; xv[5]=xf3.y; xv[6]=xf3.z; xv[7]=xf3.w;
        splitv8(xv, xh, xl);
        MFMA_CH(xh, xl, pB1h0, pB1l0, pB1h1, pB1l1, 9 * 32 + qd * 8)
      } else {
        float xv[8];
        xv[0]=xf0.x; xv[1]=xf0.y; xv[2]=xf0.z; xv[3]=xf0.w;
        xv[4]=xf1.x; xv[5]=xf1.y; xv[6]=xf1.z; xv[7]=xf1.w;
        bf16x8 xh, xl; splitv8(xv, xh, xl);
        MFMA_CH(xh, xl, pB1h0, pB1l0, pB1h1, pB1l1, 10 * 32 + qd * 8)
      }
      f32x4 zk = (kh == 0) ? (aA0 + aB0 + aC0) : (aA1 + aB1 + aC1);
      f32x4 zo = (kh == 0) ? (aA1 + aB1 + aC1) : (aA0 + aB0 + aC0);
      *(f32x4*)&zx[1][wv][lane][0] = zo;
      __syncthreads();
      zk += *(const f32x4*)&zx[1][wv ^ 4][lane][0];
      GATES_ST(zk, cs1, h1nw)
      post_flag(gBslot, t + 2);        // h1[t+1] published
    }

    // ----- B: L2[t] = gates(b2 + h1[t]@Wi2 (regs) + h2[t-1]@Wh2) -----
    {
      f32x4 aA0 = {ab2[0], ab2[0], ab2[0], ab2[0]};
      f32x4 aA1 = {ab2[1], ab2[1], ab2[1], ab2[1]};
      f32x4 aB0 = {0,0,0,0}, aB1 = {0,0,0,0}, aC0 = {0,0,0,0}, aC1 = {0,0,0,0};

      wait_flags(gAp, t + 1);          // h2[t-1] ready; h2[t] slot write-safe
      if (t > 0) {
        u64 rw2[4][4];
        LOAD_RW(rw2, h2pw)
#pragma unroll
        for (int i = 0; i < 4; ++i) {
          bf16x8 ah = hi8(rw2[i]), al = lo8(rw2[i]);
          const int koff = (8 + kh * 4 + i) * 32 + qd * 8;
          MFMA_CH(ah, al, pB2h0, pB2l0, pB2h1, pB2l1, koff)
        }
      }
      // h1[t] terms from the same fragments A just used
#pragma unroll
      for (int i = 0; i < 4; ++i) {
        const int koff = (kh * 4 + i) * 32 + qd * 8;
        MFMA_CH(h1fh[i], h1fl[i], pB2h0, pB2l0, pB2h1, pB2l1, koff)
      }
      // fetch h1[t+1] raw words for the NEXT A (posted by A above; covered by MFMAs)
      if (t < TT - 1) {
        wait_flags(gBp, t + 2);
        LOAD_RW(rwh1, h1nw)
      }
      f32x4 zk = (kh == 0) ? (aA0 + aB0 + aC0) : (aA1 + aB1 + aC1);
      f32x4 zo = (kh == 0) ? (aA1 + aB1 + aC1) : (aA0 + aB0 + aC0);
      *(f32x4*)&zx[0][wv][lane][0] = zo;
      __syncthreads();
      zk += *(const f32x4*)&zx[0][wv ^ 4][lane][0];
      GATES_ST(zk, cs2, h2cw)
      post_flag(gAslot, t + 2);        // h2[t] published
    }
  }

  // ---- dense head: logits = h2[511] @ Wd + bd (slot 1) ----
  wait_flags(gAp, TT + 1);
  if (tid < 2 * NC) {
    int r = row0 + jt * 2 + tid / NC;
    int n = tid - (tid / NC) * NC;
    float s = bd[n];
    const u32* fw = h2w + BBHH + (size_t)r * HH;
#pragma unroll 8
    for (int k = 0; k < HH; ++k) {
      u32 w = ald1(fw + k);
      s += (bf2f((u16)w) + bf2f((u16)(w >> 16))) * Wd[k * NC + n];
    }
    out[r * NC + n] = s;
  }
}

extern "C" void kernel_launch(void* const* d_in, const int* in_sizes, int n_in,
                              void* d_out, int out_size, void* d_ws, size_t ws_size,
                              hipStream_t stream) {
  const float* x   = (const float*)d_in[0];
  const float* Wi1 = (const float*)d_in[1];
  const float* Wh1 = (const float*)d_in[2];
  const float* b1  = (const float*)d_in[3];
  const float* Wi2 = (const float*)d_in[4];
  const float* Wh2 = (const float*)d_in[5];
  const float* b2  = (const float*)d_in[6];
  const float* Wd  = (const float*)d_in[7];
  const float* bd  = (const float*)d_in[8];

  char* ws = (char*)d_ws;
  // ws layout (bytes):
  //   [0, 1M)          h1w ping-pong u32 words (hi|lo<<16) [2][512][256]
  //   [1M, 2M)         h2w
  //   [2M, ..)         w1hg/w1lg (720,896 each), w2hg/w2lg (1,048,576 each)
  //   [5,636,096, +64K) flag arrays A and B (zeroed every call)
  u32* h1w = (u32*)(ws);
  u32* h2w = (u32*)(ws + 1048576u);
  u16* w1hg = (u16*)(ws + 2097152u);
  u16* w1lg = (u16*)(ws + 2097152u + 720896u);
  u16* w2hg = (u16*)(ws + 2097152u + 2u * 720896u);
  u16* w2lg = (u16*)(ws + 2097152u + 2u * 720896u + 1048576u);
  u32* flags = (u32*)(ws + 5636096u);
  float* out = (float*)d_out;

  hipMemsetAsync((void*)flags, 0, 65536, stream);
  const int total = 1024 * K1 + 1024 * K2;
  repack_kernel<<<(total + 255) / 256, 256, 0, stream>>>(
      Wi1, Wh1, Wi2, Wh2, w1hg, w1lg, w2hg, w2lg);

  void* args[] = {
    (void*)&x, (void*)&b1, (void*)&b2, (void*)&Wd, (void*)&bd,
    (void*)&w1hg, (void*)&w1lg, (void*)&w2hg, (void*)&w2lg,
    (void*)&h1w, (void*)&h2w,
    (void*)&flags, (void*)&out
  };
  // Cooperative launch purely for the co-residency guarantee; sync is custom.
  (void)hipLaunchCooperativeKernel((void*)lstm_kernel, dim3(NBLK),
                                   dim3(NTHREADS), args, 0, stream);
}